// Round 20
// baseline (231.613 us; speedup 1.0000x reference)
//
#include <hip/hip_runtime.h>
#include <math.h>

#define NN 16384
#define BB 128
#define FF 32
#define RR 20
#define EE 262144

typedef __attribute__((ext_vector_type(8))) short bf16x8;
typedef __attribute__((ext_vector_type(4))) float f32x4;
typedef __attribute__((ext_vector_type(2))) unsigned int uint32x2;

__device__ __forceinline__ float sspf(float x) {
  // softplus(x) - log(2) via HW v_exp/v_log
  float t = __expf(-fabsf(x));
  return fmaxf(x, 0.0f) + (__log2f(1.0f + t) - 1.0f) * 0.69314718055994531f;
}

__device__ __forceinline__ unsigned int pack_bf2(float a, float b) {
  unsigned int ua = __float_as_uint(a);
  ua = (ua + 0x7fffu + ((ua >> 16) & 1u)) >> 16;
  unsigned int ub = __float_as_uint(b);
  ub = (ub + 0x7fffu + ((ub >> 16) & 1u)) & 0xffff0000u;
  return ua | ub;
}

__device__ __forceinline__ unsigned short pack_bf1(float a) {
  unsigned int ua = __float_as_uint(a);
  ua = (ua + 0x7fffu + ((ua >> 16) & 1u)) >> 16;
  return (unsigned short)ua;
}

// ---------------- K1: node embeddings, x rows staged in LDS (R16-proven) ----
__global__ __launch_bounds__(256) void k_embed(const float* __restrict__ x,
        const float* __restrict__ ws, const float* __restrict__ wv,
        float4* __restrict__ hsv) {
  __shared__ float sx[32 * 516];   // 66 KB
  int t = threadIdx.x;
  int b0 = blockIdx.x * 32;        // 512 blocks
  const float4* xg = (const float4*)(x + (size_t)b0 * 512);
  for (int i = t; i < 4096; i += 256) {
    int row = i >> 7, col = i & 127;
    *(float4*)(sx + row * 516 + col * 4) = xg[i];
  }
  __syncthreads();
  int n = t >> 3, fq = t & 7;
  const float* xr = sx + n * 516;
  float acc[4][4];
#pragma unroll
  for (int k = 0; k < 4; k++)
#pragma unroll
    for (int c = 0; c < 4; c++) acc[k][c] = 0.f;
  for (int bq = 0; bq < 32; bq++) {
    float4 xs4 = *(const float4*)(xr + 4 * bq);
    float4 a0 = *(const float4*)(xr + 128 + 12 * bq);
    float4 a1 = *(const float4*)(xr + 128 + 12 * bq + 4);
    float4 a2 = *(const float4*)(xr + 128 + 12 * bq + 8);
    float xsv[4] = {xs4.x, xs4.y, xs4.z, xs4.w};
    float vv[4][3];
    vv[0][0] = a0.x; vv[0][1] = a0.y; vv[0][2] = a0.z;
    vv[1][0] = a0.w; vv[1][1] = a1.x; vv[1][2] = a1.y;
    vv[2][0] = a1.z; vv[2][1] = a1.w; vv[2][2] = a2.x;
    vv[3][0] = a2.y; vv[3][1] = a2.z; vv[3][2] = a2.w;
#pragma unroll
    for (int bb = 0; bb < 4; bb++) {
      int b = 4 * bq + bb;
      float4 w_s = *(const float4*)(ws + b * 32 + 4 * fq);
      float4 w_v = *(const float4*)(wv + b * 32 + 4 * fq);
      float wsx[4] = {w_s.x, w_s.y, w_s.z, w_s.w};
      float wvx[4] = {w_v.x, w_v.y, w_v.z, w_v.w};
#pragma unroll
      for (int k = 0; k < 4; k++) {
        acc[k][0] += xsv[bb] * wsx[k];
        acc[k][1] += vv[bb][0] * wvx[k];
        acc[k][2] += vv[bb][1] * wvx[k];
        acc[k][3] += vv[bb][2] * wvx[k];
      }
    }
  }
  const float sc = 0.088388347648318447f;  // 1/sqrt(128)
#pragma unroll
  for (int k = 0; k < 4; k++) {
    float4 o;
    o.x = acc[k][0] * sc; o.y = acc[k][1] * sc;
    o.z = acc[k][2] * sc; o.w = acc[k][3] * sc;
    hsv[(size_t)(b0 + n) * 32 + 4 * fq + k] = o;
  }
}

// ---------------- CSR build ----------------
__global__ __launch_bounds__(256) void k_count(const int* __restrict__ idx_i,
        int* __restrict__ cnt, int* __restrict__ pos) {
  int e = blockIdx.x * 256 + threadIdx.x;
  pos[e] = atomicAdd(cnt + idx_i[e], 1);
}

__global__ __launch_bounds__(256) void k_scan(const int* __restrict__ cnt,
        int* __restrict__ offs) {
  __shared__ int part[256];
  int t = threadIdx.x;
  const int4* c4 = (const int4*)(cnt + t * 64);
  int s = 0;
#pragma unroll
  for (int i = 0; i < 16; i++) {
    int4 v = c4[i];
    s += v.x + v.y + v.z + v.w;
  }
  part[t] = s;
  __syncthreads();
  if (t == 0) {
    int run = 0;
    for (int i = 0; i < 256; i++) { int v = part[i]; part[i] = run; run += v; }
    offs[NN] = run;
  }
  __syncthreads();
  int run = part[t];
  int* op = offs + t * 64;
#pragma unroll
  for (int i = 0; i < 16; i++) {
    int4 v = c4[i];
    op[4 * i + 0] = run; run += v.x;
    op[4 * i + 1] = run; run += v.y;
    op[4 * i + 2] = run; run += v.z;
    op[4 * i + 3] = run; run += v.w;
  }
}

// CSR permutation: slot_of_e (for wab scatter-write) + idx_j/Yr slot streams
__global__ __launch_bounds__(256) void k_fill(const int* __restrict__ idx_i,
        const int* __restrict__ idx_j, const float* __restrict__ Yr,
        const int* __restrict__ pos, const int* __restrict__ offs,
        int* __restrict__ slot_of_e, int* __restrict__ idxj_csr,
        float4* __restrict__ Yr_csr) {
  int e = blockIdx.x * 256 + threadIdx.x;
  int slot = offs[idx_i[e]] + pos[e];
  slot_of_e[e] = slot;
  idxj_csr[slot] = idx_j[e];
  Yr_csr[slot] = *(const float4*)(Yr + (size_t)e * 4);
}

// ---------------- fused vector output weight: Wv = w1v @ w2v * 1/sqrt(64*128) ----------------
__global__ __launch_bounds__(256) void k_wv(const float* __restrict__ w1v,
        const float* __restrict__ w2v, float* __restrict__ Wv) {
  int o = blockIdx.x * 256 + threadIdx.x;   // 8192
  int m = o >> 7, d = o & 127;
  float s = 0.f;
  for (int b = 0; b < 128; b++) s += w1v[m * 128 + b] * w2v[b * 128 + d];
  Wv[o] = s * 0.011048543456039804f;
}

// ---------------- k_prep: W2c^T in bf16, [col][k] layout for MFMA frags ----
__global__ __launch_bounds__(256) void k_prep(const float* __restrict__ W2,
        unsigned short* __restrict__ BTbf) {
  int i = blockIdx.x * 256 + threadIdx.x;   // 4096
  int col = i >> 5, k = i & 31;
  BTbf[col * 32 + k] = pack_bf1(W2[k * 192 + 6 * (col >> 2) + (col & 3)]);
}

// ---------------- k_wab: h (fp32 VALU) then MFMA bf16 GEMM, nt scatter ------
__global__ __launch_bounds__(256, 4) void k_wab(
        const float* __restrict__ fij, const float* __restrict__ rcut,
        const int* __restrict__ slot_of_e,
        const float* __restrict__ W1, const float* __restrict__ b1,
        const unsigned short* __restrict__ BTbf, const float* __restrict__ b2,
        unsigned int* __restrict__ Wab) {
  __shared__ float sfij[20 * 130];            // [r][el], 10.4 KB
  __shared__ unsigned short hbf[128 * 40];    // [edge][k], 80B rows, 10.2 KB
  __shared__ float sW1[640];
  __shared__ float sb1[32];
  __shared__ float sb2c[128];
  __shared__ float srct[128];
  __shared__ int sslot[128];
  int t = threadIdx.x;
  size_t e0 = (size_t)blockIdx.x * 128;       // 2048 blocks
  for (int i = t; i < 640; i += 256) sW1[i] = W1[i];
  if (t < 32) sb1[t] = b1[t];
  if (t < 128) {
    sb2c[t] = b2[6 * (t >> 2) + (t & 3)];
    srct[t] = rcut[e0 + t];
    sslot[t] = slot_of_e[e0 + t];
  }
  for (int i = t; i < 2560; i += 256) {
    int el = i / 20, r = i - el * 20;
    sfij[r * 130 + el] = fij[e0 * 20 + i];    // coalesced global read
  }
  __syncthreads();
  // ---- phase 1: h rows, 2 threads/edge (16 fp each) ----
  {
    int el = t >> 1, fp0 = (t & 1) * 16;
    float acc[16];
#pragma unroll
    for (int i = 0; i < 16; i++) acc[i] = sb1[fp0 + i];
#pragma unroll
    for (int r = 0; r < 20; r++) {
      float fe = sfij[r * 130 + el];
      float4 wA = *(const float4*)(sW1 + r * 32 + fp0);
      float4 wB = *(const float4*)(sW1 + r * 32 + fp0 + 4);
      float4 wC = *(const float4*)(sW1 + r * 32 + fp0 + 8);
      float4 wD = *(const float4*)(sW1 + r * 32 + fp0 + 12);
      acc[0] += fe * wA.x;  acc[1] += fe * wA.y;
      acc[2] += fe * wA.z;  acc[3] += fe * wA.w;
      acc[4] += fe * wB.x;  acc[5] += fe * wB.y;
      acc[6] += fe * wB.z;  acc[7] += fe * wB.w;
      acc[8] += fe * wC.x;  acc[9] += fe * wC.y;
      acc[10] += fe * wC.z; acc[11] += fe * wC.w;
      acc[12] += fe * wD.x; acc[13] += fe * wD.y;
      acc[14] += fe * wD.z; acc[15] += fe * wD.w;
    }
    unsigned int* hw = (unsigned int*)hbf;
#pragma unroll
    for (int i = 0; i < 8; i++)
      hw[el * 20 + (fp0 >> 1) + i] =
          pack_bf2(sspf(acc[2 * i]), sspf(acc[2 * i + 1]));
  }
  __syncthreads();
  // ---- phase 2: MFMA GEMM D[col][edge]; nontemporal uint2 scatter to Wab ----
  {
    int w = t >> 6, l = t & 63;
    int lrow = l & 15, lq = l >> 4;
    int lkq = lq * 8;                         // k-offset in shorts
    bf16x8 bfr[8];
#pragma unroll
    for (int g = 0; g < 8; g++)               // A frags: W2c^T col-tiles
      bfr[g] = *(const bf16x8*)(BTbf + (g * 16 + lrow) * 32 + lkq);
#pragma unroll
    for (int et2 = 0; et2 < 2; et2++) {
      int edge = (2 * w + et2) * 16 + lrow;
      bf16x8 af = *(const bf16x8*)(hbf + edge * 40 + lkq);   // B frag: h
      float rc = srct[edge];
      unsigned int* dst = Wab + (size_t)sslot[edge] * 64;
#pragma unroll
      for (int g = 0; g < 8; g++) {
        f32x4 z = {0.f, 0.f, 0.f, 0.f};
        f32x4 acc = __builtin_amdgcn_mfma_f32_16x16x32_bf16(bfr[g], af, z, 0, 0, 0);
        float4 bias = *(const float4*)(sb2c + g * 16 + lq * 4);
        uint32x2 o;
        o.x = pack_bf2((acc[0] + bias.x) * rc, (acc[1] + bias.y) * rc);
        o.y = pack_bf2((acc[2] + bias.z) * rc, (acc[3] + bias.w) * rc);
        __builtin_nontemporal_store(o, (uint32x2*)(dst + g * 8 + lq * 2));
      }
    }
  }
}

// ---------------- k_agg3: one wave per node; nt sequential bf16 Wab stream ----
__global__ __launch_bounds__(256, 4) void k_agg3(
        const unsigned int* __restrict__ Wu, const int* __restrict__ idxj_csr,
        const float4* __restrict__ Yr_csr, const float4* __restrict__ hsv,
        const int* __restrict__ offs, float* __restrict__ nagg) {
  int t = threadIdx.x;
  int w = t >> 6, l = t & 63;
  int n = blockIdx.x * 4 + w;          // 4096 blocks
  int f = l >> 1, kb = (l & 1) * 2;
  int start = offs[n], end = offs[n + 1];
  float a0 = 0, a1 = 0, a2 = 0, a3 = 0, a4 = 0, a5 = 0;
  if (start < end) {
    int last = end - 1;
    int i1 = start + 1 < last ? start + 1 : last;
    int i2 = start + 2 < last ? start + 2 : last;
    int j0 = idxj_csr[start];
    int j1 = idxj_csr[i1];
    int j2 = idxj_csr[i2];
    float4 y0 = Yr_csr[start];
    float4 sv0 = hsv[(size_t)j0 * 32 + f];
    float4 sv1 = hsv[(size_t)j1 * 32 + f];
    unsigned int W0 = __builtin_nontemporal_load(Wu + (size_t)start * 64 + l);
    unsigned int W1 = __builtin_nontemporal_load(Wu + (size_t)i1 * 64 + l);
    for (int ei = start; ei < end; ++ei) {
      int in1 = ei + 1 < last ? ei + 1 : last;
      int in2 = ei + 2 < last ? ei + 2 : last;
      int in3 = ei + 3 < last ? ei + 3 : last;
      float4 sv2 = hsv[(size_t)j2 * 32 + f];       // depth-2 (random, L2-hot)
      unsigned int W2r = __builtin_nontemporal_load(Wu + (size_t)in2 * 64 + l);
      float4 y1 = Yr_csr[in1];                     // depth-1 (sequential)
      int j3 = idxj_csr[in3];                      // depth-3 (sequential)
      float Wx = __uint_as_float(W0 << 16);
      float Wy = __uint_as_float(W0 & 0xffff0000u);
      float ys = y0.x, yx = y0.y, yy = y0.z, yz = y0.w;
      float ss = sv0.x, vx = sv0.y, vy = sv0.z, vz = sv0.w;
      if (kb == 0) {
        a0 += ss * ys * Wx;                                          // ch0
        a1 += (vx * yx + vy * yy + vz * yz) * 0.57735026918962576f * Wy; // ch1
      } else {
        a0 += ss * yx * Wx; a1 += ss * yy * Wx; a2 += ss * yz * Wx; // t_v1
        a3 += vx * ys * Wy; a4 += vy * ys * Wy; a5 += vz * ys * Wy; // t_v2
      }
      y0 = y1; sv0 = sv1; sv1 = sv2; W0 = W1; W1 = W2r; j2 = j3;
    }
  }
  float* na = nagg + (size_t)n * 256;
  if (kb == 0) {
    na[f] = a0;
    na[32 + f] = a1;
  } else {
    na[64 + 3 * f + 0] = a0;  na[64 + 3 * f + 1] = a1;  na[64 + 3 * f + 2] = a2;
    na[160 + 3 * f + 0] = a3; na[160 + 3 * f + 1] = a4; na[160 + 3 * f + 2] = a5;
  }
}

// ---------------- k_os12: fused os1+os2; os1 intermediate lives in LDS -------
// 32 nodes/block, grid 512. LDS: w1s 32K + w2s 64K + t1 16K = 112 KB.
__global__ __launch_bounds__(256) void k_os12(const float* __restrict__ na,
        const float* __restrict__ w1s, const float* __restrict__ w2s,
        float* __restrict__ out) {
  __shared__ float sw1[8192];      // w1s [64][128]
  __shared__ float sw2[16384];     // w2s [128][128]
  __shared__ float st1[4096];      // os1 rows [32][128]
  int t = threadIdx.x;
  for (int i = t; i < 8192; i += 256) sw1[i] = w1s[i];
  for (int i = t; i < 16384; i += 256) sw2[i] = w2s[i];
  __syncthreads();
  int dg = t & 31, ng = t >> 5;
  int d0 = dg * 4;
  int n0 = blockIdx.x * 32 + ng * 4;      // grid 512
  // ---- phase A: os1 = ssp(s_in @ w1s / 8) -> st1 ----
  {
    const float* ap = na + (size_t)n0 * 256;
    float acc[4][4] = {};
#pragma unroll
    for (int kq = 0; kq < 16; kq++) {
      float4 a[4];
#pragma unroll
      for (int j = 0; j < 4; j++) a[j] = *(const float4*)(ap + j * 256 + 4 * kq);
      float4 w0 = *(const float4*)(sw1 + (4 * kq + 0) * 128 + d0);
      float4 w1 = *(const float4*)(sw1 + (4 * kq + 1) * 128 + d0);
      float4 w2 = *(const float4*)(sw1 + (4 * kq + 2) * 128 + d0);
      float4 w3 = *(const float4*)(sw1 + (4 * kq + 3) * 128 + d0);
#pragma unroll
      for (int j = 0; j < 4; j++) {
        acc[j][0] += a[j].x * w0.x + a[j].y * w1.x + a[j].z * w2.x + a[j].w * w3.x;
        acc[j][1] += a[j].x * w0.y + a[j].y * w1.y + a[j].z * w2.y + a[j].w * w3.y;
        acc[j][2] += a[j].x * w0.z + a[j].y * w1.z + a[j].z * w2.z + a[j].w * w3.z;
        acc[j][3] += a[j].x * w0.w + a[j].y * w1.w + a[j].z * w2.w + a[j].w * w3.w;
      }
    }
#pragma unroll
    for (int j = 0; j < 4; j++) {
      float4 o;
      o.x = sspf(acc[j][0] * 0.125f);   // 1/sqrt(64)
      o.y = sspf(acc[j][1] * 0.125f);
      o.z = sspf(acc[j][2] * 0.125f);
      o.w = sspf(acc[j][3] * 0.125f);
      *(float4*)(st1 + (ng * 4 + j) * 128 + d0) = o;
    }
  }
  __syncthreads();
  // ---- phase B: out[:, :128] = (os1 @ w2s) / sqrt(128) ----
  {
    const float* bp = st1 + (size_t)(ng * 4) * 128;
    float acc[4][4] = {};
#pragma unroll
    for (int kq = 0; kq < 32; kq++) {
      float4 a[4];
#pragma unroll
      for (int j = 0; j < 4; j++) a[j] = *(const float4*)(bp + j * 128 + 4 * kq);
      float4 w0 = *(const float4*)(sw2 + (4 * kq + 0) * 128 + d0);
      float4 w1 = *(const float4*)(sw2 + (4 * kq + 1) * 128 + d0);
      float4 w2 = *(const float4*)(sw2 + (4 * kq + 2) * 128 + d0);
      float4 w3 = *(const float4*)(sw2 + (4 * kq + 3) * 128 + d0);
#pragma unroll
      for (int j = 0; j < 4; j++) {
        acc[j][0] += a[j].x * w0.x + a[j].y * w1.x + a[j].z * w2.x + a[j].w * w3.x;
        acc[j][1] += a[j].x * w0.y + a[j].y * w1.y + a[j].z * w2.y + a[j].w * w3.y;
        acc[j][2] += a[j].x * w0.z + a[j].y * w1.z + a[j].z * w2.z + a[j].w * w3.z;
        acc[j][3] += a[j].x * w0.w + a[j].y * w1.w + a[j].z * w2.w + a[j].w * w3.w;
      }
    }
    const float sc = 0.088388347648318447f;   // 1/sqrt(128)
#pragma unroll
    for (int j = 0; j < 4; j++) {
      float4 o;
      o.x = acc[j][0] * sc; o.y = acc[j][1] * sc;
      o.z = acc[j][2] * sc; o.w = acc[j][3] * sc;
      *(float4*)(out + (size_t)(n0 + j) * 512 + d0) = o;
    }
  }
}

// thread = 2 nodes x 4 d x 3 comps
__global__ __launch_bounds__(256) void k_ov(const float* __restrict__ na,
        const float* __restrict__ Wv, float* __restrict__ out) {
  __shared__ float sw[8192];       // Wv [64][128]
  int t = threadIdx.x;
  for (int i = t; i < 8192; i += 256) sw[i] = Wv[i];
  __syncthreads();
  int dg = t & 31, ng = t >> 5;
  int d0 = dg * 4;
  int n0 = blockIdx.x * 16 + ng * 2;      // grid 1024
  const float* ap = na + (size_t)n0 * 256 + 64;   // v_in row: 192 contiguous
  float acc[2][12] = {};
#pragma unroll
  for (int mq = 0; mq < 16; mq++) {
    float4 p[2][3];
#pragma unroll
    for (int j = 0; j < 2; j++) {
      p[j][0] = *(const float4*)(ap + j * 256 + 12 * mq);
      p[j][1] = *(const float4*)(ap + j * 256 + 12 * mq + 4);
      p[j][2] = *(const float4*)(ap + j * 256 + 12 * mq + 8);
    }
    float4 w0 = *(const float4*)(sw + (4 * mq + 0) * 128 + d0);
    float4 w1 = *(const float4*)(sw + (4 * mq + 1) * 128 + d0);
    float4 w2 = *(const float4*)(sw + (4 * mq + 2) * 128 + d0);
    float4 w3 = *(const float4*)(sw + (4 * mq + 3) * 128 + d0);
#pragma unroll
    for (int j = 0; j < 2; j++) {
      float vm[4][3];
      vm[0][0] = p[j][0].x; vm[0][1] = p[j][0].y; vm[0][2] = p[j][0].z;
      vm[1][0] = p[j][0].w; vm[1][1] = p[j][1].x; vm[1][2] = p[j][1].y;
      vm[2][0] = p[j][1].z; vm[2][1] = p[j][1].w; vm[2][2] = p[j][2].x;
      vm[3][0] = p[j][2].y; vm[3][1] = p[j][2].z; vm[3][2] = p[j][2].w;
      float wm[4][4];
      wm[0][0] = w0.x; wm[0][1] = w0.y; wm[0][2] = w0.z; wm[0][3] = w0.w;
      wm[1][0] = w1.x; wm[1][1] = w1.y; wm[1][2] = w1.z; wm[1][3] = w1.w;
      wm[2][0] = w2.x; wm[2][1] = w2.y; wm[2][2] = w2.z; wm[2][3] = w2.w;
      wm[3][0] = w3.x; wm[3][1] = w3.y; wm[3][2] = w3.z; wm[3][3] = w3.w;
#pragma unroll
      for (int m = 0; m < 4; m++)
#pragma unroll
        for (int i = 0; i < 4; i++)
#pragma unroll
          for (int c = 0; c < 3; c++)
            acc[j][i * 3 + c] += vm[m][c] * wm[m][i];
    }
  }
#pragma unroll
  for (int j = 0; j < 2; j++) {
    float* op = out + (size_t)(n0 + j) * 512 + 128 + 12 * dg;
    float4 o0, o1, o2;
    o0.x = acc[j][0]; o0.y = acc[j][1]; o0.z = acc[j][2]; o0.w = acc[j][3];
    o1.x = acc[j][4]; o1.y = acc[j][5]; o1.z = acc[j][6]; o1.w = acc[j][7];
    o2.x = acc[j][8]; o2.y = acc[j][9]; o2.z = acc[j][10]; o2.w = acc[j][11];
    *(float4*)op = o0;
    *(float4*)(op + 4) = o1;
    *(float4*)(op + 8) = o2;
  }
}

extern "C" void kernel_launch(void* const* d_in, const int* in_sizes, int n_in,
                              void* d_out, int out_size, void* d_ws, size_t ws_size,
                              hipStream_t stream) {
  const float* x    = (const float*)d_in[0];
  const int*   idx_i = (const int*)d_in[1];
  const int*   idx_j = (const int*)d_in[2];
  const float* fij  = (const float*)d_in[3];
  const float* rcut = (const float*)d_in[4];
  const float* Yr   = (const float*)d_in[5];
  const float* w_s  = (const float*)d_in[6];
  const float* w_v  = (const float*)d_in[7];
  const float* W1   = (const float*)d_in[8];
  const float* b1   = (const float*)d_in[9];
  const float* W2   = (const float*)d_in[10];
  const float* b2   = (const float*)d_in[11];
  const float* w1s  = (const float*)d_in[12];
  const float* w1v  = (const float*)d_in[13];
  const float* w2s  = (const float*)d_in[14];
  const float* w2v  = (const float*)d_in[15];
  float* out = (float*)d_out;

  char* ws = (char*)d_ws;
  size_t off = 0;
  auto alloc = [&](size_t bytes) {
    void* p = ws + off;
    off += (bytes + 255) & ~(size_t)255;
    return p;
  };
  float4* hsv   = (float4*)alloc((size_t)NN * 32 * 16);
  float*  nagg  = (float*)alloc((size_t)NN * 256 * 4);
  unsigned int* Wab = (unsigned int*)alloc((size_t)EE * 128 * 2);  // bf16, 67 MB
  float4* Yr_csr = (float4*)alloc((size_t)EE * 16);
  int* idxj_csr = (int*)alloc((size_t)EE * 4);
  int* slot_of_e = (int*)alloc((size_t)EE * 4);
  float* Wv     = (float*)alloc((size_t)8192 * 4);
  unsigned short* BTbf = (unsigned short*)alloc((size_t)4096 * 2);
  int* cnt      = (int*)alloc((size_t)NN * 4);
  int* offs     = (int*)alloc((size_t)(NN + 1) * 4);
  int* pos      = (int*)alloc((size_t)EE * 4);

  hipMemsetAsync(cnt, 0, (size_t)NN * 4, stream);
  k_count<<<EE / 256, 256, 0, stream>>>(idx_i, cnt, pos);
  k_scan<<<1, 256, 0, stream>>>(cnt, offs);
  k_fill<<<EE / 256, 256, 0, stream>>>(idx_i, idx_j, Yr, pos, offs,
                                       slot_of_e, idxj_csr, Yr_csr);
  k_embed<<<NN / 32, 256, 0, stream>>>(x, w_s, w_v, hsv);
  k_wv<<<32, 256, 0, stream>>>(w1v, w2v, Wv);
  k_prep<<<16, 256, 0, stream>>>(W2, BTbf);
  k_wab<<<EE / 128, 256, 0, stream>>>(fij, rcut, slot_of_e, W1, b1, BTbf, b2, Wab);
  k_agg3<<<NN / 4, 256, 0, stream>>>(Wab, idxj_csr, Yr_csr, hsv, offs, nagg);
  k_os12<<<512, 256, 0, stream>>>(nagg, w1s, w2s, out);
  k_ov<<<1024, 256, 0, stream>>>(nagg, Wv, out);
}

// Round 21
// 193.823 us; speedup vs baseline: 1.1950x; 1.1950x over previous
//
#include <hip/hip_runtime.h>
#include <math.h>

#define NN 16384
#define BB 128
#define FF 32
#define RR 20
#define EE 262144

typedef __attribute__((ext_vector_type(8))) short bf16x8;
typedef __attribute__((ext_vector_type(4))) float f32x4;

__device__ __forceinline__ float sspf(float x) {
  // softplus(x) - log(2) via HW v_exp/v_log
  float t = __expf(-fabsf(x));
  return fmaxf(x, 0.0f) + (__log2f(1.0f + t) - 1.0f) * 0.69314718055994531f;
}

__device__ __forceinline__ unsigned int pack_bf2(float a, float b) {
  unsigned int ua = __float_as_uint(a);
  ua = (ua + 0x7fffu + ((ua >> 16) & 1u)) >> 16;
  unsigned int ub = __float_as_uint(b);
  ub = (ub + 0x7fffu + ((ub >> 16) & 1u)) & 0xffff0000u;
  return ua | ub;
}

__device__ __forceinline__ unsigned short pack_bf1(float a) {
  unsigned int ua = __float_as_uint(a);
  ua = (ua + 0x7fffu + ((ua >> 16) & 1u)) >> 16;
  return (unsigned short)ua;
}

// ---------------- K1: node embeddings, x rows staged in LDS (R16-proven) ----
__global__ __launch_bounds__(256) void k_embed(const float* __restrict__ x,
        const float* __restrict__ ws, const float* __restrict__ wv,
        float4* __restrict__ hsv) {
  __shared__ float sx[32 * 516];   // 66 KB
  int t = threadIdx.x;
  int b0 = blockIdx.x * 32;        // 512 blocks
  const float4* xg = (const float4*)(x + (size_t)b0 * 512);
  for (int i = t; i < 4096; i += 256) {
    int row = i >> 7, col = i & 127;
    *(float4*)(sx + row * 516 + col * 4) = xg[i];
  }
  __syncthreads();
  int n = t >> 3, fq = t & 7;
  const float* xr = sx + n * 516;
  float acc[4][4];
#pragma unroll
  for (int k = 0; k < 4; k++)
#pragma unroll
    for (int c = 0; c < 4; c++) acc[k][c] = 0.f;
  for (int bq = 0; bq < 32; bq++) {
    float4 xs4 = *(const float4*)(xr + 4 * bq);
    float4 a0 = *(const float4*)(xr + 128 + 12 * bq);
    float4 a1 = *(const float4*)(xr + 128 + 12 * bq + 4);
    float4 a2 = *(const float4*)(xr + 128 + 12 * bq + 8);
    float xsv[4] = {xs4.x, xs4.y, xs4.z, xs4.w};
    float vv[4][3];
    vv[0][0] = a0.x; vv[0][1] = a0.y; vv[0][2] = a0.z;
    vv[1][0] = a0.w; vv[1][1] = a1.x; vv[1][2] = a1.y;
    vv[2][0] = a1.z; vv[2][1] = a1.w; vv[2][2] = a2.x;
    vv[3][0] = a2.y; vv[3][1] = a2.z; vv[3][2] = a2.w;
#pragma unroll
    for (int bb = 0; bb < 4; bb++) {
      int b = 4 * bq + bb;
      float4 w_s = *(const float4*)(ws + b * 32 + 4 * fq);
      float4 w_v = *(const float4*)(wv + b * 32 + 4 * fq);
      float wsx[4] = {w_s.x, w_s.y, w_s.z, w_s.w};
      float wvx[4] = {w_v.x, w_v.y, w_v.z, w_v.w};
#pragma unroll
      for (int k = 0; k < 4; k++) {
        acc[k][0] += xsv[bb] * wsx[k];
        acc[k][1] += vv[bb][0] * wvx[k];
        acc[k][2] += vv[bb][1] * wvx[k];
        acc[k][3] += vv[bb][2] * wvx[k];
      }
    }
  }
  const float sc = 0.088388347648318447f;  // 1/sqrt(128)
#pragma unroll
  for (int k = 0; k < 4; k++) {
    float4 o;
    o.x = acc[k][0] * sc; o.y = acc[k][1] * sc;
    o.z = acc[k][2] * sc; o.w = acc[k][3] * sc;
    hsv[(size_t)(b0 + n) * 32 + 4 * fq + k] = o;
  }
}

// ---------------- CSR build ----------------
__global__ __launch_bounds__(256) void k_count(const int* __restrict__ idx_i,
        int* __restrict__ cnt, int* __restrict__ pos) {
  int e = blockIdx.x * 256 + threadIdx.x;
  pos[e] = atomicAdd(cnt + idx_i[e], 1);
}

__global__ __launch_bounds__(256) void k_scan(const int* __restrict__ cnt,
        int* __restrict__ offs) {
  __shared__ int part[256];
  int t = threadIdx.x;
  const int4* c4 = (const int4*)(cnt + t * 64);
  int s = 0;
#pragma unroll
  for (int i = 0; i < 16; i++) {
    int4 v = c4[i];
    s += v.x + v.y + v.z + v.w;
  }
  part[t] = s;
  __syncthreads();
  if (t == 0) {
    int run = 0;
    for (int i = 0; i < 256; i++) { int v = part[i]; part[i] = run; run += v; }
    offs[NN] = run;
  }
  __syncthreads();
  int run = part[t];
  int* op = offs + t * 64;
#pragma unroll
  for (int i = 0; i < 16; i++) {
    int4 v = c4[i];
    op[4 * i + 0] = run; run += v.x;
    op[4 * i + 1] = run; run += v.y;
    op[4 * i + 2] = run; run += v.z;
    op[4 * i + 3] = run; run += v.w;
  }
}

// CSR permutation: slot_of_e (for wab scatter-write) + idx_j/Yr slot streams
__global__ __launch_bounds__(256) void k_fill(const int* __restrict__ idx_i,
        const int* __restrict__ idx_j, const float* __restrict__ Yr,
        const int* __restrict__ pos, const int* __restrict__ offs,
        int* __restrict__ slot_of_e, int* __restrict__ idxj_csr,
        float4* __restrict__ Yr_csr) {
  int e = blockIdx.x * 256 + threadIdx.x;
  int slot = offs[idx_i[e]] + pos[e];
  slot_of_e[e] = slot;
  idxj_csr[slot] = idx_j[e];
  Yr_csr[slot] = *(const float4*)(Yr + (size_t)e * 4);
}

// ---------------- fused vector output weight: Wv = w1v @ w2v * 1/sqrt(64*128) ----------------
__global__ __launch_bounds__(256) void k_wv(const float* __restrict__ w1v,
        const float* __restrict__ w2v, float* __restrict__ Wv) {
  int o = blockIdx.x * 256 + threadIdx.x;   // 8192
  int m = o >> 7, d = o & 127;
  float s = 0.f;
  for (int b = 0; b < 128; b++) s += w1v[m * 128 + b] * w2v[b * 128 + d];
  Wv[o] = s * 0.011048543456039804f;
}

// ---------------- k_prep: W2c^T in bf16, [col][k] layout for MFMA frags ----
__global__ __launch_bounds__(256) void k_prep(const float* __restrict__ W2,
        unsigned short* __restrict__ BTbf) {
  int i = blockIdx.x * 256 + threadIdx.x;   // 4096
  int col = i >> 5, k = i & 31;
  BTbf[col * 32 + k] = pack_bf1(W2[k * 192 + 6 * (col >> 2) + (col & 3)]);
}

// ---------------- k_wab: h (fp32 VALU) then MFMA bf16 GEMM, direct scatter ----
// Block = 128 edges. MFMA D[col][edge]: lane owns 4 consecutive cols of one
// edge; epilogue writes uint2 straight to Wab[slot]. LDS ~24.6 KB.
__global__ __launch_bounds__(256, 4) void k_wab(
        const float* __restrict__ fij, const float* __restrict__ rcut,
        const int* __restrict__ slot_of_e,
        const float* __restrict__ W1, const float* __restrict__ b1,
        const unsigned short* __restrict__ BTbf, const float* __restrict__ b2,
        unsigned int* __restrict__ Wab) {
  __shared__ float sfij[20 * 130];            // [r][el], 10.4 KB
  __shared__ unsigned short hbf[128 * 40];    // [edge][k], 80B rows, 10.2 KB
  __shared__ float sW1[640];
  __shared__ float sb1[32];
  __shared__ float sb2c[128];
  __shared__ float srct[128];
  __shared__ int sslot[128];
  int t = threadIdx.x;
  size_t e0 = (size_t)blockIdx.x * 128;       // 2048 blocks
  for (int i = t; i < 640; i += 256) sW1[i] = W1[i];
  if (t < 32) sb1[t] = b1[t];
  if (t < 128) {
    sb2c[t] = b2[6 * (t >> 2) + (t & 3)];
    srct[t] = rcut[e0 + t];
    sslot[t] = slot_of_e[e0 + t];
  }
  for (int i = t; i < 2560; i += 256) {
    int el = i / 20, r = i - el * 20;
    sfij[r * 130 + el] = fij[e0 * 20 + i];    // coalesced global read
  }
  __syncthreads();
  // ---- phase 1: h rows, 2 threads/edge (16 fp each) ----
  {
    int el = t >> 1, fp0 = (t & 1) * 16;
    float acc[16];
#pragma unroll
    for (int i = 0; i < 16; i++) acc[i] = sb1[fp0 + i];
#pragma unroll
    for (int r = 0; r < 20; r++) {
      float fe = sfij[r * 130 + el];
      float4 wA = *(const float4*)(sW1 + r * 32 + fp0);
      float4 wB = *(const float4*)(sW1 + r * 32 + fp0 + 4);
      float4 wC = *(const float4*)(sW1 + r * 32 + fp0 + 8);
      float4 wD = *(const float4*)(sW1 + r * 32 + fp0 + 12);
      acc[0] += fe * wA.x;  acc[1] += fe * wA.y;
      acc[2] += fe * wA.z;  acc[3] += fe * wA.w;
      acc[4] += fe * wB.x;  acc[5] += fe * wB.y;
      acc[6] += fe * wB.z;  acc[7] += fe * wB.w;
      acc[8] += fe * wC.x;  acc[9] += fe * wC.y;
      acc[10] += fe * wC.z; acc[11] += fe * wC.w;
      acc[12] += fe * wD.x; acc[13] += fe * wD.y;
      acc[14] += fe * wD.z; acc[15] += fe * wD.w;
    }
    unsigned int* hw = (unsigned int*)hbf;
#pragma unroll
    for (int i = 0; i < 8; i++)
      hw[el * 20 + (fp0 >> 1) + i] =
          pack_bf2(sspf(acc[2 * i]), sspf(acc[2 * i + 1]));
  }
  __syncthreads();
  // ---- phase 2: MFMA GEMM D[col][edge]; direct uint2 scatter to Wab ----
  {
    int w = t >> 6, l = t & 63;
    int lrow = l & 15, lq = l >> 4;
    int lkq = lq * 8;                         // k-offset in shorts
    bf16x8 bfr[8];
#pragma unroll
    for (int g = 0; g < 8; g++)               // A frags: W2c^T col-tiles
      bfr[g] = *(const bf16x8*)(BTbf + (g * 16 + lrow) * 32 + lkq);
#pragma unroll
    for (int et2 = 0; et2 < 2; et2++) {
      int edge = (2 * w + et2) * 16 + lrow;
      bf16x8 af = *(const bf16x8*)(hbf + edge * 40 + lkq);   // B frag: h
      float rc = srct[edge];
      unsigned int* dst = Wab + (size_t)sslot[edge] * 64;
#pragma unroll
      for (int g = 0; g < 8; g++) {
        f32x4 z = {0.f, 0.f, 0.f, 0.f};
        f32x4 acc = __builtin_amdgcn_mfma_f32_16x16x32_bf16(bfr[g], af, z, 0, 0, 0);
        float4 bias = *(const float4*)(sb2c + g * 16 + lq * 4);
        uint2 o;
        o.x = pack_bf2((acc[0] + bias.x) * rc, (acc[1] + bias.y) * rc);
        o.y = pack_bf2((acc[2] + bias.z) * rc, (acc[3] + bias.w) * rc);
        *(uint2*)(dst + g * 8 + lq * 2) = o;
      }
    }
  }
}

// ---------------- k_agg3: one wave per node; sequential bf16 Wab stream ------
__global__ __launch_bounds__(256, 4) void k_agg3(
        const unsigned int* __restrict__ Wu, const int* __restrict__ idxj_csr,
        const float4* __restrict__ Yr_csr, const float4* __restrict__ hsv,
        const int* __restrict__ offs, float* __restrict__ nagg) {
  int t = threadIdx.x;
  int w = t >> 6, l = t & 63;
  int n = blockIdx.x * 4 + w;          // 4096 blocks
  int f = l >> 1, kb = (l & 1) * 2;
  int start = offs[n], end = offs[n + 1];
  float a0 = 0, a1 = 0, a2 = 0, a3 = 0, a4 = 0, a5 = 0;
  if (start < end) {
    int last = end - 1;
    int i1 = start + 1 < last ? start + 1 : last;
    int i2 = start + 2 < last ? start + 2 : last;
    int j0 = idxj_csr[start];
    int j1 = idxj_csr[i1];
    int j2 = idxj_csr[i2];
    float4 y0 = Yr_csr[start];
    float4 sv0 = hsv[(size_t)j0 * 32 + f];
    float4 sv1 = hsv[(size_t)j1 * 32 + f];
    unsigned int W0 = Wu[(size_t)start * 64 + l];
    unsigned int W1 = Wu[(size_t)i1 * 64 + l];
    for (int ei = start; ei < end; ++ei) {
      int in1 = ei + 1 < last ? ei + 1 : last;
      int in2 = ei + 2 < last ? ei + 2 : last;
      int in3 = ei + 3 < last ? ei + 3 : last;
      float4 sv2 = hsv[(size_t)j2 * 32 + f];       // depth-2 (random)
      unsigned int W2r = Wu[(size_t)in2 * 64 + l]; // depth-2 (sequential)
      float4 y1 = Yr_csr[in1];                     // depth-1 (sequential)
      int j3 = idxj_csr[in3];                      // depth-3 (sequential)
      float Wx = __uint_as_float(W0 << 16);
      float Wy = __uint_as_float(W0 & 0xffff0000u);
      float ys = y0.x, yx = y0.y, yy = y0.z, yz = y0.w;
      float ss = sv0.x, vx = sv0.y, vy = sv0.z, vz = sv0.w;
      if (kb == 0) {
        a0 += ss * ys * Wx;                                          // ch0
        a1 += (vx * yx + vy * yy + vz * yz) * 0.57735026918962576f * Wy; // ch1
      } else {
        a0 += ss * yx * Wx; a1 += ss * yy * Wx; a2 += ss * yz * Wx; // t_v1
        a3 += vx * ys * Wy; a4 += vy * ys * Wy; a5 += vz * ys * Wy; // t_v2
      }
      y0 = y1; sv0 = sv1; sv1 = sv2; W0 = W1; W1 = W2r; j2 = j3;
    }
  }
  float* na = nagg + (size_t)n * 256;
  if (kb == 0) {
    na[f] = a0;
    na[32 + f] = a1;
  } else {
    na[64 + 3 * f + 0] = a0;  na[64 + 3 * f + 1] = a1;  na[64 + 3 * f + 2] = a2;
    na[160 + 3 * f + 0] = a3; na[160 + 3 * f + 1] = a4; na[160 + 3 * f + 2] = a5;
  }
}

// ---------------- output GEMMs: W in LDS [k][d], A in register tiles ----------------
__global__ __launch_bounds__(256) void k_os1(const float* __restrict__ na,
        const float* __restrict__ w1s, float* __restrict__ os1) {
  __shared__ float sw[8192];       // w1s [64][128]
  int t = threadIdx.x;
  for (int i = t; i < 8192; i += 256) sw[i] = w1s[i];
  __syncthreads();
  int dg = t & 31, ng = t >> 5;
  int d0 = dg * 4;
  int n0 = blockIdx.x * 32 + ng * 4;      // grid 512
  const float* ap = na + (size_t)n0 * 256;
  float acc[4][4] = {};
#pragma unroll
  for (int kq = 0; kq < 16; kq++) {
    float4 a[4];
#pragma unroll
    for (int j = 0; j < 4; j++) a[j] = *(const float4*)(ap + j * 256 + 4 * kq);
    float4 w0 = *(const float4*)(sw + (4 * kq + 0) * 128 + d0);
    float4 w1 = *(const float4*)(sw + (4 * kq + 1) * 128 + d0);
    float4 w2 = *(const float4*)(sw + (4 * kq + 2) * 128 + d0);
    float4 w3 = *(const float4*)(sw + (4 * kq + 3) * 128 + d0);
#pragma unroll
    for (int j = 0; j < 4; j++) {
      acc[j][0] += a[j].x * w0.x + a[j].y * w1.x + a[j].z * w2.x + a[j].w * w3.x;
      acc[j][1] += a[j].x * w0.y + a[j].y * w1.y + a[j].z * w2.y + a[j].w * w3.y;
      acc[j][2] += a[j].x * w0.z + a[j].y * w1.z + a[j].z * w2.z + a[j].w * w3.z;
      acc[j][3] += a[j].x * w0.w + a[j].y * w1.w + a[j].z * w2.w + a[j].w * w3.w;
    }
  }
#pragma unroll
  for (int j = 0; j < 4; j++) {
    float4 o;
    o.x = sspf(acc[j][0] * 0.125f);   // 1/sqrt(64)
    o.y = sspf(acc[j][1] * 0.125f);
    o.z = sspf(acc[j][2] * 0.125f);
    o.w = sspf(acc[j][3] * 0.125f);
    *(float4*)(os1 + (size_t)(n0 + j) * 128 + d0) = o;
  }
}

__global__ __launch_bounds__(256) void k_os2(const float* __restrict__ os1,
        const float* __restrict__ w2s, float* __restrict__ out) {
  __shared__ float sw[16384];      // w2s [128][128] = 64 KB
  int t = threadIdx.x;
  for (int i = t; i < 16384; i += 256) sw[i] = w2s[i];
  __syncthreads();
  int dg = t & 31, ng = t >> 5;
  int d0 = dg * 4;
  int n0 = blockIdx.x * 32 + ng * 4;      // grid 512
  const float* ap = os1 + (size_t)n0 * 128;
  float acc[4][4] = {};
#pragma unroll
  for (int kq = 0; kq < 32; kq++) {
    float4 a[4];
#pragma unroll
    for (int j = 0; j < 4; j++) a[j] = *(const float4*)(ap + j * 128 + 4 * kq);
    float4 w0 = *(const float4*)(sw + (4 * kq + 0) * 128 + d0);
    float4 w1 = *(const float4*)(sw + (4 * kq + 1) * 128 + d0);
    float4 w2 = *(const float4*)(sw + (4 * kq + 2) * 128 + d0);
    float4 w3 = *(const float4*)(sw + (4 * kq + 3) * 128 + d0);
#pragma unroll
    for (int j = 0; j < 4; j++) {
      acc[j][0] += a[j].x * w0.x + a[j].y * w1.x + a[j].z * w2.x + a[j].w * w3.x;
      acc[j][1] += a[j].x * w0.y + a[j].y * w1.y + a[j].z * w2.y + a[j].w * w3.y;
      acc[j][2] += a[j].x * w0.z + a[j].y * w1.z + a[j].z * w2.z + a[j].w * w3.z;
      acc[j][3] += a[j].x * w0.w + a[j].y * w1.w + a[j].z * w2.w + a[j].w * w3.w;
    }
  }
  const float sc = 0.088388347648318447f;   // 1/sqrt(128)
#pragma unroll
  for (int j = 0; j < 4; j++) {
    float4 o;
    o.x = acc[j][0] * sc; o.y = acc[j][1] * sc;
    o.z = acc[j][2] * sc; o.w = acc[j][3] * sc;
    *(float4*)(out + (size_t)(n0 + j) * 512 + d0) = o;
  }
}

// thread = 2 nodes x 4 d x 3 comps
__global__ __launch_bounds__(256) void k_ov(const float* __restrict__ na,
        const float* __restrict__ Wv, float* __restrict__ out) {
  __shared__ float sw[8192];       // Wv [64][128]
  int t = threadIdx.x;
  for (int i = t; i < 8192; i += 256) sw[i] = Wv[i];
  __syncthreads();
  int dg = t & 31, ng = t >> 5;
  int d0 = dg * 4;
  int n0 = blockIdx.x * 16 + ng * 2;      // grid 1024
  const float* ap = na + (size_t)n0 * 256 + 64;   // v_in row: 192 contiguous
  float acc[2][12] = {};
#pragma unroll
  for (int mq = 0; mq < 16; mq++) {
    float4 p[2][3];
#pragma unroll
    for (int j = 0; j < 2; j++) {
      p[j][0] = *(const float4*)(ap + j * 256 + 12 * mq);
      p[j][1] = *(const float4*)(ap + j * 256 + 12 * mq + 4);
      p[j][2] = *(const float4*)(ap + j * 256 + 12 * mq + 8);
    }
    float4 w0 = *(const float4*)(sw + (4 * mq + 0) * 128 + d0);
    float4 w1 = *(const float4*)(sw + (4 * mq + 1) * 128 + d0);
    float4 w2 = *(const float4*)(sw + (4 * mq + 2) * 128 + d0);
    float4 w3 = *(const float4*)(sw + (4 * mq + 3) * 128 + d0);
#pragma unroll
    for (int j = 0; j < 2; j++) {
      float vm[4][3];
      vm[0][0] = p[j][0].x; vm[0][1] = p[j][0].y; vm[0][2] = p[j][0].z;
      vm[1][0] = p[j][0].w; vm[1][1] = p[j][1].x; vm[1][2] = p[j][1].y;
      vm[2][0] = p[j][1].z; vm[2][1] = p[j][1].w; vm[2][2] = p[j][2].x;
      vm[3][0] = p[j][2].y; vm[3][1] = p[j][2].z; vm[3][2] = p[j][2].w;
      float wm[4][4];
      wm[0][0] = w0.x; wm[0][1] = w0.y; wm[0][2] = w0.z; wm[0][3] = w0.w;
      wm[1][0] = w1.x; wm[1][1] = w1.y; wm[1][2] = w1.z; wm[1][3] = w1.w;
      wm[2][0] = w2.x; wm[2][1] = w2.y; wm[2][2] = w2.z; wm[2][3] = w2.w;
      wm[3][0] = w3.x; wm[3][1] = w3.y; wm[3][2] = w3.z; wm[3][3] = w3.w;
#pragma unroll
      for (int m = 0; m < 4; m++)
#pragma unroll
        for (int i = 0; i < 4; i++)
#pragma unroll
          for (int c = 0; c < 3; c++)
            acc[j][i * 3 + c] += vm[m][c] * wm[m][i];
    }
  }
#pragma unroll
  for (int j = 0; j < 2; j++) {
    float* op = out + (size_t)(n0 + j) * 512 + 128 + 12 * dg;
    float4 o0, o1, o2;
    o0.x = acc[j][0]; o0.y = acc[j][1]; o0.z = acc[j][2]; o0.w = acc[j][3];
    o1.x = acc[j][4]; o1.y = acc[j][5]; o1.z = acc[j][6]; o1.w = acc[j][7];
    o2.x = acc[j][8]; o2.y = acc[j][9]; o2.z = acc[j][10]; o2.w = acc[j][11];
    *(float4*)op = o0;
    *(float4*)(op + 4) = o1;
    *(float4*)(op + 8) = o2;
  }
}

extern "C" void kernel_launch(void* const* d_in, const int* in_sizes, int n_in,
                              void* d_out, int out_size, void* d_ws, size_t ws_size,
                              hipStream_t stream) {
  const float* x    = (const float*)d_in[0];
  const int*   idx_i = (const int*)d_in[1];
  const int*   idx_j = (const int*)d_in[2];
  const float* fij  = (const float*)d_in[3];
  const float* rcut = (const float*)d_in[4];
  const float* Yr   = (const float*)d_in[5];
  const float* w_s  = (const float*)d_in[6];
  const float* w_v  = (const float*)d_in[7];
  const float* W1   = (const float*)d_in[8];
  const float* b1   = (const float*)d_in[9];
  const float* W2   = (const float*)d_in[10];
  const float* b2   = (const float*)d_in[11];
  const float* w1s  = (const float*)d_in[12];
  const float* w1v  = (const float*)d_in[13];
  const float* w2s  = (const float*)d_in[14];
  const float* w2v  = (const float*)d_in[15];
  float* out = (float*)d_out;

  char* ws = (char*)d_ws;
  size_t off = 0;
  auto alloc = [&](size_t bytes) {
    void* p = ws + off;
    off += (bytes + 255) & ~(size_t)255;
    return p;
  };
  float4* hsv   = (float4*)alloc((size_t)NN * 32 * 16);
  float*  nagg  = (float*)alloc((size_t)NN * 256 * 4);
  unsigned int* Wab = (unsigned int*)alloc((size_t)EE * 128 * 2);  // bf16, 67 MB
  float*  os1   = (float*)alloc((size_t)NN * 128 * 4);
  float4* Yr_csr = (float4*)alloc((size_t)EE * 16);
  int* idxj_csr = (int*)alloc((size_t)EE * 4);
  int* slot_of_e = (int*)alloc((size_t)EE * 4);
  float* Wv     = (float*)alloc((size_t)8192 * 4);
  unsigned short* BTbf = (unsigned short*)alloc((size_t)4096 * 2);
  int* cnt      = (int*)alloc((size_t)NN * 4);
  int* offs     = (int*)alloc((size_t)(NN + 1) * 4);
  int* pos      = (int*)alloc((size_t)EE * 4);

  hipMemsetAsync(cnt, 0, (size_t)NN * 4, stream);
  k_count<<<EE / 256, 256, 0, stream>>>(idx_i, cnt, pos);
  k_scan<<<1, 256, 0, stream>>>(cnt, offs);
  k_fill<<<EE / 256, 256, 0, stream>>>(idx_i, idx_j, Yr, pos, offs,
                                       slot_of_e, idxj_csr, Yr_csr);
  k_embed<<<NN / 32, 256, 0, stream>>>(x, w_s, w_v, hsv);
  k_wv<<<32, 256, 0, stream>>>(w1v, w2v, Wv);
  k_prep<<<16, 256, 0, stream>>>(W2, BTbf);
  k_wab<<<EE / 128, 256, 0, stream>>>(fij, rcut, slot_of_e, W1, b1, BTbf, b2, Wab);
  k_agg3<<<NN / 4, 256, 0, stream>>>(Wab, idxj_csr, Yr_csr, hsv, offs, nagg);
  k_os1<<<512, 256, 0, stream>>>(nagg, w1s, os1);
  k_os2<<<512, 256, 0, stream>>>(os1, w2s, out);
  k_ov<<<1024, 256, 0, stream>>>(nagg, Wv, out);
}